// Round 7
// baseline (466.334 us; speedup 1.0000x reference)
//
#include <hip/hip_runtime.h>
#include <cstdint>
#include <cstddef>

// ---------------------------------------------------------------------------
// JambaMambaBlock on MI355X (gfx950)
// Pipeline: rmsnorm -> GEMM1(in_proj, split epilogue: x fp32 / silu(z) bf16)
//           -> depthwise conv+silu -> GEMM2(x_proj, softplus epilogue)
//           -> chunked SSM scan (3 phases) -> GEMM3(out_proj, +residual)
// GEMMs (round-10): 256x256 tile, BK=64, 8 waves, wave tile 128x64, 2-buffer
//   LDS (128 KB), 8 phases per 2 K-tiles, frag banks one phase deep.
//   Round-7 change: phase order is now [STG ; RD(frags for p+1) ; MFMA_p ;
//   VMW ; BAR]  (was [MFMA ; STG ; RD ; VMW ; BAR]). Round-6 PMC arithmetic:
//   phase wall 1322 cyc = MFMA 620 + LDS-port 704 SERIAL -- reads issued at
//   phase end stalled the next phase's MFMA on lgkmcnt (sched_barrier pins
//   them). Issuing reads BEFORE the MFMA cluster drains the LDS port under
//   the matrix pipe; ledger unchanged (reads move earlier = strictly safer
//   WAR; every RAW still covered by a prior-phase VMW + barrier).
//   VMW(4) even-phase tails; add-rotate swizzle (0 conflicts, r1-r6).
// Scan (round-6, kept): wave-uniform row addressing scalarized via
//   readfirstlane; SGPR row bases + SALU bumps; saddr-form loads.
// Epilogue: 4 LDS-staged 64x256 strips (pad 268), coalesced f32x4 stores,
//   fully static acc indexing (rule-20 scratch fix, verified round 3).
// ---------------------------------------------------------------------------

typedef __bf16 bf16_t;
typedef __attribute__((ext_vector_type(8))) __bf16 bf16x8;
typedef __attribute__((ext_vector_type(4))) __bf16 bf16x4;
typedef __attribute__((ext_vector_type(4))) float f32x4;

#define D_MODEL 2048
#define D_STATE 16
#define B_SZ 2
#define T_LEN 2048
#define N_ROWS (B_SZ * T_LEN)        // 4096
#define N_PAD  2304                  // x_proj rows padded 2080 -> 9*256
#define N_CHUNK 32
#define L_CHUNK (T_LEN / N_CHUNK)    // 64
#define LOG2E 1.4426950408889634f

__device__ __forceinline__ void load_lds16(const void* g, void* l) {
    __builtin_amdgcn_global_load_lds(
        (const __attribute__((address_space(1))) void*)(uintptr_t)g,
        (__attribute__((address_space(3))) void*)(uintptr_t)l,
        16, 0, 0);
}

#define VMW(n) asm volatile("s_waitcnt vmcnt(" #n ")" ::: "memory")
#define BARG() do { __builtin_amdgcn_s_barrier(); __builtin_amdgcn_sched_barrier(0); } while (0)

// ---------------- weight casts ----------------
__global__ __launch_bounds__(256) void cast_w13(
    const float* __restrict__ w1, const float* __restrict__ w3,
    bf16_t* __restrict__ d1, bf16_t* __restrict__ d3)
{
    int i = blockIdx.x * 256 + threadIdx.x;
    const int n1 = 4096 * 2048 / 4;
    if (i < n1) {
        f32x4 v = ((const f32x4*)w1)[i];
        ((bf16x4*)d1)[i] = __builtin_convertvector(v, bf16x4);
    } else {
        int j = i - n1;      // < 2048*2048/4
        f32x4 v = ((const f32x4*)w3)[j];
        ((bf16x4*)d3)[j] = __builtin_convertvector(v, bf16x4);
    }
}

// x_proj_w (2080 x 2048) -> bf16 padded to (2304 x 2048), pad rows zero
__global__ __launch_bounds__(256) void cast_pad_w2(
    const float* __restrict__ s, bf16_t* __restrict__ d)
{
    int i = blockIdx.x * 256 + threadIdx.x;   // over 2304*2048
    int row = i >> 11;
    int col = i & 2047;
    float v = (row < 2080) ? s[(size_t)row * 2048 + col] : 0.f;
    d[i] = (bf16_t)v;
}

// ---------------- rmsnorm -> bf16 (vectorized f32x4 / bf16x4) -------------
__global__ __launch_bounds__(256) void rmsnorm_kernel(
    const float* __restrict__ x, const float* __restrict__ w,
    bf16_t* __restrict__ xn)
{
    int row = blockIdx.x;
    int tid = threadIdx.x;
    const f32x4* xr = (const f32x4*)(x + (size_t)row * D_MODEL);
    f32x4 v0 = xr[tid];
    f32x4 v1 = xr[tid + 256];
    float ss = 0.f;
    #pragma unroll
    for (int e = 0; e < 4; ++e) { ss = fmaf(v0[e], v0[e], ss); ss = fmaf(v1[e], v1[e], ss); }
    #pragma unroll
    for (int o = 32; o > 0; o >>= 1) ss += __shfl_down(ss, o, 64);
    __shared__ float red[4];
    if ((tid & 63) == 0) red[tid >> 6] = ss;
    __syncthreads();
    float tot = red[0] + red[1] + red[2] + red[3];
    float scale = rsqrtf(tot * (1.f / D_MODEL) + 1e-6f);
    const f32x4* w4 = (const f32x4*)w;
    f32x4 m0 = v0 * w4[tid] * scale;
    f32x4 m1 = v1 * w4[tid + 256] * scale;
    bf16x4* xo = (bf16x4*)(xn + (size_t)row * D_MODEL);
    xo[tid]       = __builtin_convertvector(m0, bf16x4);
    xo[tid + 256] = __builtin_convertvector(m1, bf16x4);
}

// ---------------- bf16 GEMM: C[M,N] = A[M,K] @ B[N,K]^T -------------------
// 256x256 tile, BK=64 (2 k-slices of 32), 512 threads, 2-buffer LDS,
// pipelined-fragment 8-phase schedule, reads-at-phase-top (round 7).
// gridDim.x MUST be 16. K must be a multiple of 128.
// MODE 0 (GEMM1): bn<8 -> out0 fp32 (ldc 2048); bn>=8 -> out1 = bf16 silu(v)
// MODE 1 (GEMM2): out0 fp32 ldc N_PAD; softplus applied when bn<8
// MODE 2 (GEMM3): out0 = v + add, fp32 ldc 2048
template<int MODE>
__global__ __launch_bounds__(512, 2) void gemm_bt(
    const bf16_t* __restrict__ A, const bf16_t* __restrict__ Bw, int K,
    float* __restrict__ out0, bf16_t* __restrict__ out1,
    const float* __restrict__ add)
{
    __shared__ __align__(16) char smem[131072];
    // layout: buf*65536 + mat*32768 + kslice*16384 ; each slot = [256][32] bf16
    char* const ldsAp = smem;
    char* const ldsBp = smem + 32768;

    const int tid  = threadIdx.x;
    // bijective XCD swizzle (nwg divisible by 8 for all launches)
    const int nwg = gridDim.x * gridDim.y;
    const int lin = blockIdx.x + gridDim.x * blockIdx.y;
    const int wg  = (lin & 7) * (nwg >> 3) + (lin >> 3);
    const int bm  = wg & 15;           // gridDim.x == 16 always
    const int bn  = wg >> 4;

    const int lane = tid & 63;
    const int wave = tid >> 6;
    const int wm   = wave >> 2;      // 0..1  (row half of 256)
    const int wn   = wave & 3;       // 0..3  (col quarter of 256)
    const int fr   = lane & 15;
    const int quad = lane >> 4;

    // staging: thread covers 16B chunks (rows rS, rS+128) x chunk cS of each
    // [256][32] slot. Add-rotate swizzle: physical chunk p of row r holds
    // logical chunk (p - (r>>1))&3 -> pre-rotate the GLOBAL column, LDS dest
    // stays linear (global_load_lds rule). (r+128)>>1 == r>>1 (mod 4).
    const int rS   = tid >> 2;                    // 0..127
    const int cS   = tid & 3;
    const int gcol = ((cS - ((rS >> 1) & 3)) & 3) * 8;
    // running stage pointers: every stage of a stream advances +32 columns
    const bf16_t* sAn = A  + (size_t)(bm * 256 + rS) * K + gcol;
    const bf16_t* sBn = Bw + (size_t)(bn * 256 + rS) * K + gcol;

    // fragment read offsets (elements within a [256][32] slot)
    const int swz  = ((quad + ((fr >> 1) & 3)) & 3) * 8;
    const int aOff = (wm * 128 + fr) * 32 + swz;   // + i*512 per 16-row frag
    const int bOff = (wn * 64  + fr) * 32 + swz;   // + j*512

    f32x4 acc[8][4];
    #pragma unroll
    for (int i = 0; i < 8; ++i)
        #pragma unroll
        for (int j = 0; j < 4; ++j) acc[i][j] = {0.f, 0.f, 0.f, 0.f};

    bf16x8 afr[2][4];   // A-frag double bank (loaded phase p, used p+1)
    bf16x8 bfr[2][4];   // B-frag double bank (loaded even phase, used 2 phases)

#define STG_A(b, s) do { \
        char* l_ = ldsAp + (b) * 65536 + (s) * 16384 + tid * 16; \
        load_lds16(sAn, l_); load_lds16(sAn + (size_t)128 * K, l_ + 8192); \
        sAn += 32; } while (0)
#define STG_B(b, s) do { \
        char* l_ = ldsBp + (b) * 65536 + (s) * 16384 + tid * 16; \
        load_lds16(sBn, l_); load_lds16(sBn + (size_t)128 * K, l_ + 8192); \
        sBn += 32; } while (0)

// 16-MFMA cluster: acc rows MIH*4.., A bank MAB, B bank MBB (all literal).
#define MFMA16(MIH, MAB, MBB)                                                 \
    __builtin_amdgcn_s_setprio(1);                                            \
    _Pragma("unroll")                                                         \
    for (int i = 0; i < 4; ++i)                                               \
        _Pragma("unroll")                                                     \
        for (int j = 0; j < 4; ++j)                                           \
            acc[(MIH)*4+i][j] = __builtin_amdgcn_mfma_f32_16x16x32_bf16(      \
                afr[MAB][i], bfr[MBB][j], acc[(MIH)*4+i][j], 0, 0, 0);        \
    __builtin_amdgcn_s_setprio(0);

// read next phase's A frags (half RIH of slot [RBUF][RS]) into bank RAB
#define RD_A(RBUF, RS, RIH, RAB) {                                            \
    const bf16_t* pA_ = (const bf16_t*)(ldsAp + (RBUF)*65536 + (RS)*16384);   \
    _Pragma("unroll")                                                         \
    for (int i = 0; i < 4; ++i)                                               \
        afr[RAB][i] = *(const bf16x8*)(pA_ + aOff + ((RIH)*4+i)*512); }

// read next k-slice's B frags (slot [RBUF][RS]) into bank RBB
#define RD_B(RBUF, RS, RBB) {                                                 \
    const bf16_t* pB_ = (const bf16_t*)(ldsBp + (RBUF)*65536 + (RS)*16384);   \
    _Pragma("unroll")                                                         \
    for (int j = 0; j < 4; ++j)                                               \
        bfr[RBB][j] = *(const bf16x8*)(pB_ + bOff + j*512); }

    // prologue: stage 7 slots (14 loads); VMW(6) retires buf0 (loads 1-8);
    // preload ph1 fragments (buf0 s0: B bank0 + A rows 0-3 bank0).
    STG_B(0, 0); STG_A(0, 0); STG_B(0, 1); STG_A(0, 1);
    STG_B(1, 0); STG_A(1, 0); STG_B(1, 1);
    VMW(6); BARG();
    RD_B(0, 0, 0) RD_A(0, 0, 0, 0)

    // Phase (round 7): [stage ; reads for NEXT phase ; MFMA on prior reads ;
    // tail-VMW ; barrier]. Reads issued before the 16-MFMA cluster so the
    // LDS port drains under the matrix pipe; consumed only after the barrier.
    const int NI = K >> 7;             // 16 for K=2048
    for (int I = 0; I < NI - 1; ++I) {
        // ph1: stage A t(2I+1)k1; read (0,0)IH1->A1; compute (0,0)IH0
        STG_A(1,1); RD_A(0,0,1,1) MFMA16(0,0,0)                  BARG();
        // ph2: stage B t2k0; read (0,1) B->b1, A0-3->A0; compute (0,0)IH1
        STG_B(0,0); RD_B(0,1,1) RD_A(0,1,0,0) MFMA16(1,1,0) VMW(4); BARG();
        // ph3: stage A t2k0; read (0,1)IH1->A1; compute (0,1)IH0
        STG_A(0,0); RD_A(0,1,1,1) MFMA16(0,0,1)                  BARG();
        // ph4: stage B t2k1; read (1,0) B->b0, A0-3->A0; compute (0,1)IH1
        STG_B(0,1); RD_B(1,0,0) RD_A(1,0,0,0) MFMA16(1,1,1) VMW(4); BARG();
        // ph5: stage A t2k1; read (1,0)IH1->A1; compute (1,0)IH0
        STG_A(0,1); RD_A(1,0,1,1) MFMA16(0,0,0)                  BARG();
        // ph6: stage B t3k0; read (1,1) B->b1, A0-3->A0; compute (1,0)IH1
        STG_B(1,0); RD_B(1,1,1) RD_A(1,1,0,0) MFMA16(1,1,0) VMW(4); BARG();
        // ph7: stage A t3k0; read (1,1)IH1->A1; compute (1,1)IH0
        STG_A(1,0); RD_A(1,1,1,1) MFMA16(0,0,1)                  BARG();
        // ph8: stage B t3k1; read next (0,0) B->b0, A0-3->A0; compute (1,1)IH1
        STG_B(1,1); RD_B(0,0,0) RD_A(0,0,0,0) MFMA16(1,1,1) VMW(4); BARG();
    }
    // tail iteration: only ph1 stages (final A k1 slot); VMW(4)@ph2 retires
    // prev-ph7 A(1,0) + prev-ph8 B(1,1); VMW(0)@ph4 retires ph1's A(1,1).
    STG_A(1,1); RD_A(0,0,1,1) MFMA16(0,0,0)              BARG();
    RD_B(0,1,1) RD_A(0,1,0,0) MFMA16(1,1,0)      VMW(4); BARG();
    RD_A(0,1,1,1) MFMA16(0,0,1)                          BARG();
    RD_B(1,0,0) RD_A(1,0,0,0) MFMA16(1,1,1)      VMW(0); BARG();
    RD_A(1,0,1,1) MFMA16(0,0,0)                          BARG();
    RD_B(1,1,1) RD_A(1,1,0,0) MFMA16(1,1,0)              BARG();
    RD_A(1,1,1,1) MFMA16(0,0,1)                          BARG();
    MFMA16(1,1,1)
#undef STG_A
#undef STG_B
#undef MFMA16
#undef RD_A
#undef RD_B

    // ---- LDS-staged coalesced epilogue: 4 strips of 64 rows x 256 cols ----
    // acc[i][j][rr]: row = wm*128 + i*16 + quad*4 + rr, col = wn*64 + j*16 + fr
    // Fully static acc indexing (s-loop unrolled) -- rule-20 scratch fix.
    float* const cs = (float*)smem;        // [64][268] fp32, 68.6 KB
    __syncthreads();
    #pragma unroll
    for (int s = 0; s < 4; ++s) {
        if (wm == (s >> 1)) {
            #pragma unroll
            for (int ii = 0; ii < 4; ++ii)
                #pragma unroll
                for (int j = 0; j < 4; ++j)
                    #pragma unroll
                    for (int rr = 0; rr < 4; ++rr)
                        cs[(ii * 16 + quad * 4 + rr) * 268 + wn * 64 + j * 16 + fr]
                            = acc[(s & 1) * 4 + ii][j][rr];
        }
        __syncthreads();
        #pragma unroll
        for (int k = 0; k < 8; ++k) {
            const int idx = tid + k * 512;       // 0..4095
            const int row = idx >> 6;            // 0..63
            const int c4  = (idx & 63) << 2;     // 0..252
            f32x4 v = *(const f32x4*)(cs + row * 268 + c4);
            const int gr = bm * 256 + s * 64 + row;
            const int gc = bn * 256 + c4;
            if (MODE == 0) {
                if (bn < 8) {
                    *(f32x4*)&out0[(size_t)gr * 2048 + gc] = v;
                } else {
                    bf16x4 o;
                    #pragma unroll
                    for (int e = 0; e < 4; ++e) {
                        float sv = v[e];
                        o[e] = (bf16_t)(sv / (1.f + __expf(-sv)));
                    }
                    *(bf16x4*)&out1[(size_t)gr * 2048 + (gc - 2048)] = o;
                }
            } else if (MODE == 1) {
                if (bn < 8) {
                    #pragma unroll
                    for (int e = 0; e < 4; ++e) {
                        float sv = v[e];
                        v[e] = fmaxf(sv, 0.f) + __logf(1.f + __expf(-fabsf(sv)));
                    }
                }
                *(f32x4*)&out0[(size_t)gr * N_PAD + gc] = v;
            } else {
                f32x4 a4 = *(const f32x4*)&add[(size_t)gr * 2048 + gc];
                *(f32x4*)&out0[(size_t)gr * 2048 + gc] = v + a4;
            }
        }
        __syncthreads();
    }
}

// ---------------- depthwise causal conv(4) + silu (bf16 out) ----------
// xb: x-branch fp32, pitch 2048
__global__ __launch_bounds__(256) void conv_silu_kernel(
    const float* __restrict__ xb, const float* __restrict__ cw,
    const float* __restrict__ cb, bf16_t* __restrict__ xs_b)
{
    int id = blockIdx.x * 256 + threadIdx.x;  // B*(T/8)*D = 2^20
    int d  = id & 2047;
    int tb = (id >> 11) & 255;
    int b  = id >> 19;
    float w0 = cw[d * 4 + 0], w1 = cw[d * 4 + 1], w2 = cw[d * 4 + 2], w3 = cw[d * 4 + 3];
    float bias = cb[d];
    int t0 = tb * 8;
    size_t base = (size_t)b * T_LEN;
    float v[11];
    #pragma unroll
    for (int i = 0; i < 11; ++i) {
        int t = t0 - 3 + i;
        v[i] = (t >= 0) ? xb[(base + t) * 2048 + d] : 0.f;
    }
    #pragma unroll
    for (int j = 0; j < 8; ++j) {
        float s = bias + w0 * v[j] + w1 * v[j + 1] + w2 * v[j + 2] + w3 * v[j + 3];
        float sl = s / (1.f + __expf(-s));
        xs_b[(base + t0 + j) * D_MODEL + d] = (bf16_t)sl;
    }
}

// ---------------- chunked SSM scan ----------------
// Wave wi in [0,8192): c = wi&31, dg = (wi>>5)&127, b = wi>>12.
// Lane: nq = lane&3 (state quad), dsub = lane>>2; dd = dg*16 + dsub.
// Row index (b,t) is WAVE-UNIFORM: derive wave id via readfirstlane so all
// row bases are SGPR pointers advanced by SALU adds; loads are saddr-form
// with loop-invariant VGPR column offsets (round-6: kills ~half the VALU).
// proj cols <2048 hold da = softplus(delta_raw) (from GEMM2 epilogue).
// scratch layout: [c][b][dd][n] flat = (c*4096 + b*2048 + dd)*16 + n
#define PF 4   // prefetch depth (register slots)

// phase 1: local scan with zero init; store decay product + local final state
__global__ __launch_bounds__(256) void scan_phase1(
    const float* __restrict__ proj, const bf16_t* __restrict__ xs,
    const float* __restrict__ A_log,
    float* __restrict__ Aprod, float* __restrict__ hfin)
{
    const int wiu  = __builtin_amdgcn_readfirstlane(
                         blockIdx.x * 4 + (threadIdx.x >> 6));
    const int lane = threadIdx.x & 63;
    const int nq   = lane & 3;
    const int dsub = lane >> 2;
    const int c  = wiu & 31;
    const int dg = (wiu >> 5) & 127;
    const int b  = wiu >> 12;
    const int dd = dg * 16 + dsub;

    float A2[4], h[4];
    #pragma unroll
    for (int j = 0; j < 4; ++j) {
        A2[j] = -__expf(A_log[dd * D_STATE + nq * 4 + j]) * LOG2E;
        h[j] = 0.f;
    }
    float sda = 0.f;    // running sum of da: Aprod = exp2(A2[j]*sda) at end

    const int t0 = c * L_CHUNK;
    // scalar (SGPR) row bases; divergent column offsets are loop-invariant
    const float*  pr = proj + (size_t)(b * T_LEN + t0) * N_PAD;
    const bf16_t* px = xs   + (size_t)(b * T_LEN + t0) * D_MODEL;
    const int offB = D_MODEL + nq * 4;

    float p_da[PF], p_xv[PF];
    f32x4 p_B[PF];
    #pragma unroll
    for (int u = 0; u < PF; ++u) {
        p_da[u] = pr[dd];
        p_B[u]  = *(const f32x4*)(pr + offB);
        p_xv[u] = (float)px[dd];
        pr += N_PAD; px += D_MODEL;
    }
    for (int g = 0; g < L_CHUNK / PF - 1; ++g) {
        #pragma unroll
        for (int u = 0; u < PF; ++u) {
            float da = p_da[u], xv = p_xv[u];
            f32x4 Bv = p_B[u];
            p_da[u] = pr[dd];
            p_B[u]  = *(const f32x4*)(pr + offB);
            p_xv[u] = (float)px[dd];
            pr += N_PAD; px += D_MODEL;
            float dx = da * xv;
            sda += da;
            #pragma unroll
            for (int j = 0; j < 4; ++j) {
                float a = exp2f(da * A2[j]);
                h[j] = fmaf(a, h[j], dx * Bv[j]);
            }
        }
    }
    #pragma unroll
    for (int u = 0; u < PF; ++u) {   // final group, no prefetch
        float da = p_da[u], xv = p_xv[u];
        f32x4 Bv = p_B[u];
        float dx = da * xv;
        sda += da;
        #pragma unroll
        for (int j = 0; j < 4; ++j) {
            float a = exp2f(da * A2[j]);
            h[j] = fmaf(a, h[j], dx * Bv[j]);
        }
    }
    size_t o = ((size_t)c * 4096 + b * 2048 + dd) * D_STATE + nq * 4;
    *(f32x4*)(Aprod + o) = f32x4{exp2f(A2[0] * sda), exp2f(A2[1] * sda),
                                 exp2f(A2[2] * sda), exp2f(A2[3] * sda)};
    *(f32x4*)(hfin  + o) = f32x4{h[0], h[1], h[2], h[3]};
}

// phase 2: serial combine across chunks. In-place converts hfin -> h_init
// per chunk, and writes the exact final state h_out.
__global__ __launch_bounds__(256) void scan_phase2(
    const float* __restrict__ h_in, const float* __restrict__ Aprod,
    float* __restrict__ hfin, float* __restrict__ h_out)
{
    int g = blockIdx.x * 256 + threadIdx.x;   // (b*2048+dd)*16+n, 65536 total
    float h = h_in[g];
    for (int c = 0; c < N_CHUNK; ++c) {
        size_t o = (size_t)c * 65536 + g;
        float a   = Aprod[o];
        float loc = hfin[o];
        hfin[o] = h;                 // becomes h_init for chunk c
        h = fmaf(a, h, loc);
    }
    h_out[g] = h;
}

// phase 3: replay each chunk from its exact initial state; emit gated y.
// zg holds silu(z) in bf16 (from GEMM1 epilogue).
__global__ __launch_bounds__(256) void scan_phase3(
    const float* __restrict__ proj, const bf16_t* __restrict__ xs,
    const bf16_t* __restrict__ zg, const float* __restrict__ A_log,
    const float* __restrict__ Dv, const float* __restrict__ hinit,
    bf16_t* __restrict__ yg)
{
    const int wiu  = __builtin_amdgcn_readfirstlane(
                         blockIdx.x * 4 + (threadIdx.x >> 6));
    const int lane = threadIdx.x & 63;
    const int nq   = lane & 3;
    const int dsub = lane >> 2;
    const int c  = wiu & 31;
    const int dg = (wiu >> 5) & 127;
    const int b  = wiu >> 12;
    const int dd = dg * 16 + dsub;

    float A2[4], h[4];
    size_t o = ((size_t)c * 4096 + b * 2048 + dd) * D_STATE + nq * 4;
    #pragma unroll
    for (int j = 0; j < 4; ++j) {
        A2[j] = -__expf(A_log[dd * D_STATE + nq * 4 + j]) * LOG2E;
        h[j]  = hinit[o + j];
    }
    float Dd = Dv[dd];

    const int t0 = c * L_CHUNK;
    // scalar (SGPR) row bases: prefetch bases advance at issue, store base
    // advances at consume (lags by PF rows).
    const float*  pr = proj + (size_t)(b * T_LEN + t0) * N_PAD;
    const bf16_t* px = xs   + (size_t)(b * T_LEN + t0) * D_MODEL;
    const bf16_t* pz = zg   + (size_t)(b * T_LEN + t0) * 2048;
    bf16_t*       py = yg   + (size_t)(b * T_LEN + t0) * D_MODEL;
    const int offB = D_MODEL + nq * 4;
    const int offC = D_MODEL + D_STATE + nq * 4;

    float p_da[PF], p_xv[PF], p_sz[PF];
    f32x4 p_B[PF], p_C[PF];
    #pragma unroll
    for (int u = 0; u < PF; ++u) {
        p_da[u] = pr[dd];
        p_B[u]  = *(const f32x4*)(pr + offB);
        p_C[u]  = *(const f32x4*)(pr + offC);
        p_xv[u] = (float)px[dd];
        p_sz[u] = (float)pz[dd];
        pr += N_PAD; px += D_MODEL; pz += 2048;
    }

#define P3_STEP(da, xv, sz, Bv, Cv)                                       \
    {                                                                     \
        float dx = da * xv;                                               \
        float yp = 0.f;                                                   \
        _Pragma("unroll")                                                 \
        for (int j = 0; j < 4; ++j) {                                     \
            float a = exp2f(da * A2[j]);                                  \
            h[j] = fmaf(a, h[j], dx * Bv[j]);                             \
            yp = fmaf(h[j], Cv[j], yp);                                   \
        }                                                                 \
        yp += __shfl_xor(yp, 1, 64);                                      \
        yp += __shfl_xor(yp, 2, 64);                                      \
        if (nq == 0) {                                                    \
            float y = fmaf(Dd, xv, yp);                                   \
            py[dd] = (bf16_t)(y * sz);                                    \
        }                                                                 \
        py += D_MODEL;                                                    \
    }

    for (int g = 0; g < L_CHUNK / PF - 1; ++g) {
        #pragma unroll
        for (int u = 0; u < PF; ++u) {
            float da = p_da[u], xv = p_xv[u], sz = p_sz[u];
            f32x4 Bv = p_B[u], Cv = p_C[u];
            p_da[u] = pr[dd];
            p_B[u]  = *(const f32x4*)(pr + offB);
            p_C[u]  = *(const f32x4*)(pr + offC);
            p_xv[u] = (float)px[dd];
            p_sz[u] = (float)pz[dd];
            pr += N_PAD; px += D_MODEL; pz += 2048;
            P3_STEP(da, xv, sz, Bv, Cv)
        }
    }
    #pragma unroll
    for (int u = 0; u < PF; ++u) {   // final group, no prefetch
        float da = p_da[u], xv = p_xv[u], sz = p_sz[u];
        f32x4 Bv = p_B[u], Cv = p_C[u];
        P3_STEP(da, xv, sz, Bv, Cv)
    }
#undef P3_STEP
}

// ---------------------------------------------------------------------------
extern "C" void kernel_launch(void* const* d_in, const int* in_sizes, int n_in,
                              void* d_out, int out_size, void* d_ws, size_t ws_size,
                              hipStream_t stream)
{
    const float* x    = (const float*)d_in[0];
    const float* h0   = (const float*)d_in[1];
    const float* nw   = (const float*)d_in[2];
    const float* w_in = (const float*)d_in[3];
    const float* cw   = (const float*)d_in[4];
    const float* cb   = (const float*)d_in[5];
    const float* w_x  = (const float*)d_in[6];
    const float* alog = (const float*)d_in[7];
    const float* dv   = (const float*)d_in[8];
    const float* w_out= (const float*)d_in[9];
    float* out  = (float*)d_out;
    float* hout = out + (size_t)N_ROWS * D_MODEL;

    char* ws = (char*)d_ws;
    size_t off = 0;
    auto alloc = [&](size_t bytes) -> void* {
        void* p = ws + off;
        off += (bytes + 255) & ~(size_t)255;
        return p;
    };
    bf16_t* W1  = (bf16_t*)alloc((size_t)4096 * 2048 * 2);   // in_proj bf16
    bf16_t* W2  = (bf16_t*)alloc((size_t)N_PAD * 2048 * 2);  // x_proj bf16 padded
    bf16_t* W3  = (bf16_t*)alloc((size_t)2048 * 2048 * 2);   // out_proj bf16
    bf16_t* XN  = (bf16_t*)alloc((size_t)N_ROWS * 2048 * 2); // normed x bf16
    float*  XB  = (float*) alloc((size_t)N_ROWS * 2048 * 4); // x-branch fp32
    bf16_t* ZG  = (bf16_t*)alloc((size_t)N_ROWS * 2048 * 2); // silu(z) bf16
    float*  PROJ= (float*) alloc((size_t)N_ROWS * N_PAD * 4);// x_proj out (da|B|C)
    float* APROD= (float*) alloc((size_t)N_CHUNK * 4096 * D_STATE * 4);
    float* HFIN = (float*) alloc((size_t)N_CHUNK * 4096 * D_STATE * 4);
    // aliases (lifetimes disjoint in stream order):
    bf16_t* XSb = W1;   // conv bf16 out (W1 dead after GEMM1; lives thru scan)
    bf16_t* YG  = XN;   // gated y bf16  (XN dead after GEMM1)

    // weight casts
    cast_w13<<<(4096 * 2048 / 4 + 2048 * 2048 / 4) / 256, 256, 0, stream>>>(w_in, w_out, W1, W3);
    cast_pad_w2<<<(N_PAD * 2048) / 256, 256, 0, stream>>>(w_x, W2);

    // 1) rmsnorm
    rmsnorm_kernel<<<N_ROWS, 256, 0, stream>>>(x, nw, XN);
    // 2) xz = xn @ W_in^T; epilogue splits x fp32 / silu(z) bf16
    gemm_bt<0><<<dim3(16, 16), 512, 0, stream>>>(XN, W1, 2048, XB, ZG, nullptr);
    // 3) conv + silu (bf16 out)
    conv_silu_kernel<<<(B_SZ * (T_LEN / 8) * D_MODEL) / 256, 256, 0, stream>>>(XB, cw, cb, XSb);
    // 4) proj = xssm @ W_x^T; epilogue applies softplus to delta cols
    gemm_bt<1><<<dim3(16, N_PAD / 256), 512, 0, stream>>>(XSb, W2, 2048, PROJ, nullptr, nullptr);
    // 5) chunked scan: 8192 waves, scalar-base addressing, depth-4 prefetch
    scan_phase1<<<2048, 256, 0, stream>>>(PROJ, XSb, alog, APROD, HFIN);
    scan_phase2<<<256, 256, 0, stream>>>(h0, APROD, HFIN, hout);
    scan_phase3<<<2048, 256, 0, stream>>>(PROJ, XSb, ZG, alog, dv, HFIN, YG);
    // 6) out = x + yg @ W_out^T
    gemm_bt<2><<<dim3(16, 8), 512, 0, stream>>>(YG, W3, 2048, out, nullptr, x);

    (void)in_sizes; (void)n_in; (void)out_size; (void)ws_size;
}

// Round 8
// 462.459 us; speedup vs baseline: 1.0084x; 1.0084x over previous
//
#include <hip/hip_runtime.h>
#include <cstdint>
#include <cstddef>

// ---------------------------------------------------------------------------
// JambaMambaBlock on MI355X (gfx950)
// Pipeline: rmsnorm -> GEMM1(in_proj, split epilogue: x fp32 / silu(z) bf16)
//           -> depthwise conv+silu -> GEMM2(x_proj, softplus epilogue)
//           -> chunked SSM scan (3 phases) -> GEMM3(out_proj, +residual)
// Round-8 changes:
//  (1) GEMM2/3 move to a 128x128-tile m97-replica kernel (gemm128): 4 waves,
//      BK=32, single-buffer global_load_lds + 2 syncthreads/tile (the
//      measured-912TF learn_hip structure), grids 32x17=544 / 32x16=512
//      blocks -> machine saturated with 3-4 blocks/CU co-resident
//      (round-7 PMC: 144/128-block 256^2 launches idled 44-50% of CUs for
//      a full 72us block-time each). N_PAD back to 2176 (17*128).
//  (2) scan: shfl_xor pair -> DPP quad-perm adds (VALU-only, kills 2 DS ops
//      + lgkm latency per step); prefetch depth PF 4->8.
// GEMM1 keeps the 256x256 8-phase kernel (exact 256-block grid, 954 TF).
// ---------------------------------------------------------------------------

typedef __bf16 bf16_t;
typedef __attribute__((ext_vector_type(8))) __bf16 bf16x8;
typedef __attribute__((ext_vector_type(4))) __bf16 bf16x4;
typedef __attribute__((ext_vector_type(4))) float f32x4;

#define D_MODEL 2048
#define D_STATE 16
#define B_SZ 2
#define T_LEN 2048
#define N_ROWS (B_SZ * T_LEN)        // 4096
#define N_PAD  2176                  // x_proj rows padded 2080 -> 17*128
#define N_CHUNK 32
#define L_CHUNK (T_LEN / N_CHUNK)    // 64
#define LOG2E 1.4426950408889634f

__device__ __forceinline__ void load_lds16(const void* g, void* l) {
    __builtin_amdgcn_global_load_lds(
        (const __attribute__((address_space(1))) void*)(uintptr_t)g,
        (__attribute__((address_space(3))) void*)(uintptr_t)l,
        16, 0, 0);
}

#define VMW(n) asm volatile("s_waitcnt vmcnt(" #n ")" ::: "memory")
#define BARG() do { __builtin_amdgcn_s_barrier(); __builtin_amdgcn_sched_barrier(0); } while (0)

// DPP quad reduction: sum over the 4 lanes of each quad (lane^1 then lane^2).
// Pure VALU (v_mov_b32 dpp + v_add) -- no DS op, no lgkm wait.
__device__ __forceinline__ float quad_add(float v) {
    int t = __builtin_amdgcn_mov_dpp(__builtin_bit_cast(int, v),
                                     0xB1, 0xF, 0xF, true);  // quad_perm 1,0,3,2
    v += __builtin_bit_cast(float, t);
    t = __builtin_amdgcn_mov_dpp(__builtin_bit_cast(int, v),
                                 0x4E, 0xF, 0xF, true);      // quad_perm 2,3,0,1
    v += __builtin_bit_cast(float, t);
    return v;
}

// ---------------- weight casts ----------------
__global__ __launch_bounds__(256) void cast_w13(
    const float* __restrict__ w1, const float* __restrict__ w3,
    bf16_t* __restrict__ d1, bf16_t* __restrict__ d3)
{
    int i = blockIdx.x * 256 + threadIdx.x;
    const int n1 = 4096 * 2048 / 4;
    if (i < n1) {
        f32x4 v = ((const f32x4*)w1)[i];
        ((bf16x4*)d1)[i] = __builtin_convertvector(v, bf16x4);
    } else {
        int j = i - n1;      // < 2048*2048/4
        f32x4 v = ((const f32x4*)w3)[j];
        ((bf16x4*)d3)[j] = __builtin_convertvector(v, bf16x4);
    }
}

// x_proj_w (2080 x 2048) -> bf16 padded to (2176 x 2048), pad rows zero
__global__ __launch_bounds__(256) void cast_pad_w2(
    const float* __restrict__ s, bf16_t* __restrict__ d)
{
    int i = blockIdx.x * 256 + threadIdx.x;   // over 2176*2048
    int row = i >> 11;
    int col = i & 2047;
    float v = (row < 2080) ? s[(size_t)row * 2048 + col] : 0.f;
    d[i] = (bf16_t)v;
}

// ---------------- rmsnorm -> bf16 (vectorized f32x4 / bf16x4) -------------
__global__ __launch_bounds__(256) void rmsnorm_kernel(
    const float* __restrict__ x, const float* __restrict__ w,
    bf16_t* __restrict__ xn)
{
    int row = blockIdx.x;
    int tid = threadIdx.x;
    const f32x4* xr = (const f32x4*)(x + (size_t)row * D_MODEL);
    f32x4 v0 = xr[tid];
    f32x4 v1 = xr[tid + 256];
    float ss = 0.f;
    #pragma unroll
    for (int e = 0; e < 4; ++e) { ss = fmaf(v0[e], v0[e], ss); ss = fmaf(v1[e], v1[e], ss); }
    #pragma unroll
    for (int o = 32; o > 0; o >>= 1) ss += __shfl_down(ss, o, 64);
    __shared__ float red[4];
    if ((tid & 63) == 0) red[tid >> 6] = ss;
    __syncthreads();
    float tot = red[0] + red[1] + red[2] + red[3];
    float scale = rsqrtf(tot * (1.f / D_MODEL) + 1e-6f);
    const f32x4* w4 = (const f32x4*)w;
    f32x4 m0 = v0 * w4[tid] * scale;
    f32x4 m1 = v1 * w4[tid + 256] * scale;
    bf16x4* xo = (bf16x4*)(xn + (size_t)row * D_MODEL);
    xo[tid]       = __builtin_convertvector(m0, bf16x4);
    xo[tid + 256] = __builtin_convertvector(m1, bf16x4);
}

// ---------------- 256x256 bf16 GEMM (GEMM1 only) --------------------------
// C[M,N] = A[M,K] @ B[N,K]^T. 8-phase pipelined-fragment schedule (round 7).
// gridDim.x MUST be 16. bn<8 -> out0 fp32 (ldc 2048); bn>=8 -> out1 bf16
// silu(v) (ldc 2048, col-2048).
__global__ __launch_bounds__(512, 2) void gemm_bt(
    const bf16_t* __restrict__ A, const bf16_t* __restrict__ Bw, int K,
    float* __restrict__ out0, bf16_t* __restrict__ out1)
{
    __shared__ __align__(16) char smem[131072];
    char* const ldsAp = smem;
    char* const ldsBp = smem + 32768;

    const int tid  = threadIdx.x;
    const int nwg = gridDim.x * gridDim.y;
    const int lin = blockIdx.x + gridDim.x * blockIdx.y;
    const int wg  = (lin & 7) * (nwg >> 3) + (lin >> 3);
    const int bm  = wg & 15;
    const int bn  = wg >> 4;

    const int lane = tid & 63;
    const int wave = tid >> 6;
    const int wm   = wave >> 2;
    const int wn   = wave & 3;
    const int fr   = lane & 15;
    const int quad = lane >> 4;

    const int rS   = tid >> 2;                    // 0..127
    const int cS   = tid & 3;
    const int gcol = ((cS - ((rS >> 1) & 3)) & 3) * 8;
    const bf16_t* sAn = A  + (size_t)(bm * 256 + rS) * K + gcol;
    const bf16_t* sBn = Bw + (size_t)(bn * 256 + rS) * K + gcol;

    const int swz  = ((quad + ((fr >> 1) & 3)) & 3) * 8;
    const int aOff = (wm * 128 + fr) * 32 + swz;
    const int bOff = (wn * 64  + fr) * 32 + swz;

    f32x4 acc[8][4];
    #pragma unroll
    for (int i = 0; i < 8; ++i)
        #pragma unroll
        for (int j = 0; j < 4; ++j) acc[i][j] = {0.f, 0.f, 0.f, 0.f};

    bf16x8 afr[2][4];
    bf16x8 bfr[2][4];

#define STG_A(b, s) do { \
        char* l_ = ldsAp + (b) * 65536 + (s) * 16384 + tid * 16; \
        load_lds16(sAn, l_); load_lds16(sAn + (size_t)128 * K, l_ + 8192); \
        sAn += 32; } while (0)
#define STG_B(b, s) do { \
        char* l_ = ldsBp + (b) * 65536 + (s) * 16384 + tid * 16; \
        load_lds16(sBn, l_); load_lds16(sBn + (size_t)128 * K, l_ + 8192); \
        sBn += 32; } while (0)
#define MFMA16(MIH, MAB, MBB)                                                 \
    __builtin_amdgcn_s_setprio(1);                                            \
    _Pragma("unroll")                                                         \
    for (int i = 0; i < 4; ++i)                                               \
        _Pragma("unroll")                                                     \
        for (int j = 0; j < 4; ++j)                                           \
            acc[(MIH)*4+i][j] = __builtin_amdgcn_mfma_f32_16x16x32_bf16(      \
                afr[MAB][i], bfr[MBB][j], acc[(MIH)*4+i][j], 0, 0, 0);        \
    __builtin_amdgcn_s_setprio(0);
#define RD_A(RBUF, RS, RIH, RAB) {                                            \
    const bf16_t* pA_ = (const bf16_t*)(ldsAp + (RBUF)*65536 + (RS)*16384);   \
    _Pragma("unroll")                                                         \
    for (int i = 0; i < 4; ++i)                                               \
        afr[RAB][i] = *(const bf16x8*)(pA_ + aOff + ((RIH)*4+i)*512); }
#define RD_B(RBUF, RS, RBB) {                                                 \
    const bf16_t* pB_ = (const bf16_t*)(ldsBp + (RBUF)*65536 + (RS)*16384);   \
    _Pragma("unroll")                                                         \
    for (int j = 0; j < 4; ++j)                                               \
        bfr[RBB][j] = *(const bf16x8*)(pB_ + bOff + j*512); }

    STG_B(0, 0); STG_A(0, 0); STG_B(0, 1); STG_A(0, 1);
    STG_B(1, 0); STG_A(1, 0); STG_B(1, 1);
    VMW(6); BARG();
    RD_B(0, 0, 0) RD_A(0, 0, 0, 0)

    const int NI = K >> 7;
    for (int I = 0; I < NI - 1; ++I) {
        STG_A(1,1); RD_A(0,0,1,1) MFMA16(0,0,0)                  BARG();
        STG_B(0,0); RD_B(0,1,1) RD_A(0,1,0,0) MFMA16(1,1,0) VMW(4); BARG();
        STG_A(0,0); RD_A(0,1,1,1) MFMA16(0,0,1)                  BARG();
        STG_B(0,1); RD_B(1,0,0) RD_A(1,0,0,0) MFMA16(1,1,1) VMW(4); BARG();
        STG_A(0,1); RD_A(1,0,1,1) MFMA16(0,0,0)                  BARG();
        STG_B(1,0); RD_B(1,1,1) RD_A(1,1,0,0) MFMA16(1,1,0) VMW(4); BARG();
        STG_A(1,0); RD_A(1,1,1,1) MFMA16(0,0,1)                  BARG();
        STG_B(1,1); RD_B(0,0,0) RD_A(0,0,0,0) MFMA16(1,1,1) VMW(4); BARG();
    }
    STG_A(1,1); RD_A(0,0,1,1) MFMA16(0,0,0)              BARG();
    RD_B(0,1,1) RD_A(0,1,0,0) MFMA16(1,1,0)      VMW(4); BARG();
    RD_A(0,1,1,1) MFMA16(0,0,1)                          BARG();
    RD_B(1,0,0) RD_A(1,0,0,0) MFMA16(1,1,1)      VMW(0); BARG();
    RD_A(1,0,1,1) MFMA16(0,0,0)                          BARG();
    RD_B(1,1,1) RD_A(1,1,0,0) MFMA16(1,1,0)              BARG();
    RD_A(1,1,1,1) MFMA16(0,0,1)                          BARG();
    MFMA16(1,1,1)
#undef STG_A
#undef STG_B
#undef MFMA16
#undef RD_A
#undef RD_B

    // LDS-staged coalesced epilogue: 4 strips of 64 rows x 256 cols.
    float* const cs = (float*)smem;        // [64][268] fp32
    __syncthreads();
    #pragma unroll
    for (int s = 0; s < 4; ++s) {
        if (wm == (s >> 1)) {
            #pragma unroll
            for (int ii = 0; ii < 4; ++ii)
                #pragma unroll
                for (int j = 0; j < 4; ++j)
                    #pragma unroll
                    for (int rr = 0; rr < 4; ++rr)
                        cs[(ii * 16 + quad * 4 + rr) * 268 + wn * 64 + j * 16 + fr]
                            = acc[(s & 1) * 4 + ii][j][rr];
        }
        __syncthreads();
        #pragma unroll
        for (int k = 0; k < 8; ++k) {
            const int idx = tid + k * 512;
            const int row = idx >> 6;
            const int c4  = (idx & 63) << 2;
            f32x4 v = *(const f32x4*)(cs + row * 268 + c4);
            const int gr = bm * 256 + s * 64 + row;
            const int gc = bn * 256 + c4;
            if (bn < 8) {
                *(f32x4*)&out0[(size_t)gr * 2048 + gc] = v;
            } else {
                bf16x4 o;
                #pragma unroll
                for (int e = 0; e < 4; ++e) {
                    float sv = v[e];
                    o[e] = (bf16_t)(sv / (1.f + __expf(-sv)));
                }
                *(bf16x4*)&out1[(size_t)gr * 2048 + (gc - 2048)] = o;
            }
        }
        __syncthreads();
    }
}

// ---------------- 128x128 bf16 GEMM (GEMM2/GEMM3) -------------------------
// m97-replica: 4 waves, BK=32, single-buffer global_load_lds staging,
// 2 syncthreads per K-tile. Grid-filling (544/512 blocks, 3-4 blocks/CU).
// gridDim.x MUST be 32; nwg divisible by 8.
// MODE 1: out0 fp32 ldc N_PAD; softplus applied when bn<16 (cols<2048)
// MODE 2: out0 = v + add, fp32 ldc 2048
template<int MODE>
__global__ __launch_bounds__(256, 2) void gemm128(
    const bf16_t* __restrict__ A, const bf16_t* __restrict__ Bw, int K,
    float* __restrict__ out0, const float* __restrict__ add)
{
    __shared__ __align__(16) bf16_t lA[128 * 32];   // 8 KB
    __shared__ __align__(16) bf16_t lB[128 * 32];   // 8 KB
    __shared__ __align__(16) float  cs[32 * 132];   // epilogue strip

    const int tid = threadIdx.x;
    const int nwg = gridDim.x * gridDim.y;
    const int lin = blockIdx.x + gridDim.x * blockIdx.y;
    const int wg  = (lin & 7) * (nwg >> 3) + (lin >> 3);
    const int bm  = wg & 31;          // gridDim.x == 32
    const int bn  = wg >> 5;

    const int lane = tid & 63;
    const int wave = tid >> 6;
    const int wm   = wave & 1;        // row half (64 rows)
    const int wn   = wave >> 1;       // col half (64 cols)
    const int fr   = lane & 15;
    const int quad = lane >> 4;

    // staging: thread covers rows rS and rS+64, chunk cS of [128][32] slot;
    // add-rotate swizzle on the GLOBAL column (LDS dest linear).
    // (r+64)>>1 = r>>1 + 32 == r>>1 (mod 4) -> same gcol for both rows.
    const int rS   = tid >> 2;        // 0..63
    const int cS   = tid & 3;
    const int gcol = ((cS - ((rS >> 1) & 3)) & 3) * 8;
    const bf16_t* sA = A  + (size_t)(bm * 128 + rS) * K + gcol;
    const bf16_t* sB = Bw + (size_t)(bn * 128 + rS) * K + gcol;

    const int swz  = ((quad + ((fr >> 1) & 3)) & 3) * 8;
    const int aOff = (wm * 64 + fr) * 32 + swz;   // + i*512 per 16-row frag
    const int bOff = (wn * 64 + fr) * 32 + swz;

    f32x4 acc[4][4];
    #pragma unroll
    for (int i = 0; i < 4; ++i)
        #pragma unroll
        for (int j = 0; j < 4; ++j) acc[i][j] = {0.f, 0.f, 0.f, 0.f};

    const int nt = K >> 5;
    for (int kt = 0; kt < nt; ++kt) {
        load_lds16(sA,                 (char*)lA + tid * 16);
        load_lds16(sA + (size_t)64 * K,(char*)lA + 4096 + tid * 16);
        load_lds16(sB,                 (char*)lB + tid * 16);
        load_lds16(sB + (size_t)64 * K,(char*)lB + 4096 + tid * 16);
        sA += 32; sB += 32;
        __syncthreads();

        bf16x8 af[4], bv[4];
        #pragma unroll
        for (int i = 0; i < 4; ++i) af[i] = *(const bf16x8*)(lA + aOff + i * 512);
        #pragma unroll
        for (int j = 0; j < 4; ++j) bv[j] = *(const bf16x8*)(lB + bOff + j * 512);
        __builtin_amdgcn_s_setprio(1);
        #pragma unroll
        for (int i = 0; i < 4; ++i)
            #pragma unroll
            for (int j = 0; j < 4; ++j)
                acc[i][j] = __builtin_amdgcn_mfma_f32_16x16x32_bf16(
                    af[i], bv[j], acc[i][j], 0, 0, 0);
        __builtin_amdgcn_s_setprio(0);
        __syncthreads();
    }

    // LDS-staged epilogue (round-0 verified): 4 strips of 32 rows x 128 cols.
    // acc(i,j,rr): row = wm*64 + i*16 + quad*4 + rr, col = wn*64 + j*16 + fr
    const int lrow0 = wm * 16 + quad * 4;
    const int lcol0 = wn * 64 + fr;
    for (int i = 0; i < 4; ++i) {
        __syncthreads();
        #pragma unroll
        for (int j = 0; j < 4; ++j)
            #pragma unroll
            for (int rr = 0; rr < 4; ++rr)
                cs[(lrow0 + rr) * 132 + lcol0 + j * 16] = acc[i][j][rr];
        __syncthreads();
        #pragma unroll
        for (int k = 0; k < 4; ++k) {
            int f4  = tid + k * 256;       // 0..1023
            int row = f4 >> 5;             // 0..31
            int c4  = (f4 & 31) * 4;       // 0..124
            f32x4 v = *(const f32x4*)&cs[row * 132 + c4];
            int gr = bm * 128 + i * 16 + ((row < 16) ? row : (48 + row));
            int gc = bn * 128 + c4;
            if (MODE == 1) {
                if (bn < 16) {
                    #pragma unroll
                    for (int e = 0; e < 4; ++e) {
                        float s = v[e];
                        v[e] = fmaxf(s, 0.f) + __logf(1.f + __expf(-fabsf(s)));
                    }
                }
                *(f32x4*)&out0[(size_t)gr * N_PAD + gc] = v;
            } else {
                f32x4 a4 = *(const f32x4*)&add[(size_t)gr * 2048 + gc];
                *(f32x4*)&out0[(size_t)gr * 2048 + gc] = v + a4;
            }
        }
    }
}

// ---------------- depthwise causal conv(4) + silu (bf16 out) ----------
__global__ __launch_bounds__(256) void conv_silu_kernel(
    const float* __restrict__ xb, const float* __restrict__ cw,
    const float* __restrict__ cb, bf16_t* __restrict__ xs_b)
{
    int id = blockIdx.x * 256 + threadIdx.x;  // B*(T/8)*D = 2^20
    int d  = id & 2047;
    int tb = (id >> 11) & 255;
    int b  = id >> 19;
    float w0 = cw[d * 4 + 0], w1 = cw[d * 4 + 1], w2 = cw[d * 4 + 2], w3 = cw[d * 4 + 3];
    float bias = cb[d];
    int t0 = tb * 8;
    size_t base = (size_t)b * T_LEN;
    float v[11];
    #pragma unroll
    for (int i = 0; i < 11; ++i) {
        int t = t0 - 3 + i;
        v[i] = (t >= 0) ? xb[(base + t) * 2048 + d] : 0.f;
    }
    #pragma unroll
    for (int j = 0; j < 8; ++j) {
        float s = bias + w0 * v[j] + w1 * v[j + 1] + w2 * v[j + 2] + w3 * v[j + 3];
        float sl = s / (1.f + __expf(-s));
        xs_b[(base + t0 + j) * D_MODEL + d] = (bf16_t)sl;
    }
}

// ---------------- chunked SSM scan ----------------
// Wave wi in [0,8192): c = wi&31, dg = (wi>>5)&127, b = wi>>12.
// Lane: nq = lane&3 (state quad), dsub = lane>>2; dd = dg*16 + dsub.
// Row bases are SGPR (readfirstlane + SALU bumps); saddr-form loads.
// proj cols <2048 hold da = softplus(delta_raw) (from GEMM2 epilogue).
// scratch layout: [c][b][dd][n] flat = (c*4096 + b*2048 + dd)*16 + n
#define PF 8   // prefetch depth (register slots)

// phase 1: local scan with zero init; store decay product + local final state
__global__ __launch_bounds__(256) void scan_phase1(
    const float* __restrict__ proj, const bf16_t* __restrict__ xs,
    const float* __restrict__ A_log,
    float* __restrict__ Aprod, float* __restrict__ hfin)
{
    const int wiu  = __builtin_amdgcn_readfirstlane(
                         blockIdx.x * 4 + (threadIdx.x >> 6));
    const int lane = threadIdx.x & 63;
    const int nq   = lane & 3;
    const int dsub = lane >> 2;
    const int c  = wiu & 31;
    const int dg = (wiu >> 5) & 127;
    const int b  = wiu >> 12;
    const int dd = dg * 16 + dsub;

    float A2[4], h[4];
    #pragma unroll
    for (int j = 0; j < 4; ++j) {
        A2[j] = -__expf(A_log[dd * D_STATE + nq * 4 + j]) * LOG2E;
        h[j] = 0.f;
    }
    float sda = 0.f;    // running sum of da: Aprod = exp2(A2[j]*sda) at end

    const int t0 = c * L_CHUNK;
    const float*  pr = proj + (size_t)(b * T_LEN + t0) * N_PAD;
    const bf16_t* px = xs   + (size_t)(b * T_LEN + t0) * D_MODEL;
    const int offB = D_MODEL + nq * 4;

    float p_da[PF], p_xv[PF];
    f32x4 p_B[PF];
    #pragma unroll
    for (int u = 0; u < PF; ++u) {
        p_da[u] = pr[dd];
        p_B[u]  = *(const f32x4*)(pr + offB);
        p_xv[u] = (float)px[dd];
        pr += N_PAD; px += D_MODEL;
    }
    for (int g = 0; g < L_CHUNK / PF - 1; ++g) {
        #pragma unroll
        for (int u = 0; u < PF; ++u) {
            float da = p_da[u], xv = p_xv[u];
            f32x4 Bv = p_B[u];
            p_da[u] = pr[dd];
            p_B[u]  = *(const f32x4*)(pr + offB);
            p_xv[u] = (float)px[dd];
            pr += N_PAD; px += D_MODEL;
            float dx = da * xv;
            sda += da;
            #pragma unroll
            for (int j = 0; j < 4; ++j) {
                float a = exp2f(da * A2[j]);
                h[j] = fmaf(a, h[j], dx * Bv[j]);
            }
        }
    }
    #pragma unroll
    for (int u = 0; u < PF; ++u) {   // final group, no prefetch
        float da = p_da[u], xv = p_xv[u];
        f32x4 Bv = p_B[u];
        float dx = da * xv;
        sda += da;
        #pragma unroll
        for (int j = 0; j < 4; ++j) {
            float a = exp2f(da * A2[j]);
            h[j] = fmaf(a, h[j], dx * Bv[j]);
        }
    }
    size_t o = ((size_t)c * 4096 + b * 2048 + dd) * D_STATE + nq * 4;
    *(f32x4*)(Aprod + o) = f32x4{exp2f(A2[0] * sda), exp2f(A2[1] * sda),
                                 exp2f(A2[2] * sda), exp2f(A2[3] * sda)};
    *(f32x4*)(hfin  + o) = f32x4{h[0], h[1], h[2], h[3]};
}

// phase 2: serial combine across chunks. In-place converts hfin -> h_init
// per chunk, and writes the exact final state h_out.
__global__ __launch_bounds__(256) void scan_phase2(
    const float* __restrict__ h_in, const float* __restrict__ Aprod,
    float* __restrict__ hfin, float* __restrict__ h_out)
{
    int g = blockIdx.x * 256 + threadIdx.x;   // (b*2048+dd)*16+n, 65536 total
    float h = h_in[g];
    for (int c = 0; c < N_CHUNK; ++c) {
        size_t o = (size_t)c * 65536 + g;
        float a   = Aprod[o];
        float loc = hfin[o];
        hfin[o] = h;                 // becomes h_init for chunk c
        h = fmaf(a, h, loc);
    }
    h_out[g] = h;
}

// phase 3: replay each chunk from its exact initial state; emit gated y.
__global__ __launch_bounds__(256) void scan_phase3(
    const float* __restrict__ proj, const bf16_t* __restrict__ xs,
    const bf16_t* __restrict__ zg, const float* __restrict__ A_log,
    const float* __restrict__ Dv, const float* __restrict__ hinit,
    bf16_t* __restrict__ yg)
{
    const int wiu  = __builtin_amdgcn_readfirstlane(
                         blockIdx.x * 4 + (threadIdx.x >> 6));
    const int lane = threadIdx.x & 63;
    const int nq   = lane & 3;
    const int dsub = lane >> 2;
    const int c  = wiu & 31;
    const int dg = (wiu >> 5) & 127;
    const int b  = wiu >> 12;
    const int dd = dg * 16 + dsub;

    float A2[4], h[4];
    size_t o = ((size_t)c * 4096 + b * 2048 + dd) * D_STATE + nq * 4;
    #pragma unroll
    for (int j = 0; j < 4; ++j) {
        A2[j] = -__expf(A_log[dd * D_STATE + nq * 4 + j]) * LOG2E;
        h[j]  = hinit[o + j];
    }
    float Dd = Dv[dd];

    const int t0 = c * L_CHUNK;
    const float*  pr = proj + (size_t)(b * T_LEN + t0) * N_PAD;
    const bf16_t* px = xs   + (size_t)(b * T_LEN + t0) * D_MODEL;
    const bf16_t* pz = zg   + (size_t)(b * T_LEN + t0) * 2048;
    bf16_t*       py = yg   + (size_t)(b * T_LEN + t0) * D_MODEL;
    const int offB = D_MODEL + nq * 4;
    const int offC = D_MODEL + D_STATE + nq * 4;

    float p_da[PF], p_xv[PF], p_sz[PF];
    f32x4 p_B[PF], p_C[PF];
    #pragma unroll
    for (int u = 0; u < PF; ++u) {
        p_da[u] = pr[dd];
        p_B[u]  = *(const f32x4*)(pr + offB);
        p_C[u]  = *(const f32x4*)(pr + offC);
        p_xv[u] = (float)px[dd];
        p_sz[u] = (float)pz[dd];
        pr += N_PAD; px += D_MODEL; pz += 2048;
    }

#define P3_STEP(da, xv, sz, Bv, Cv)                                       \
    {                                                                     \
        float dx = da * xv;                                               \
        float yp = 0.f;                                                   \
        _Pragma("unroll")                                                 \
        for (int j = 0; j < 4; ++j) {                                     \
            float a = exp2f(da * A2[j]);                                  \
            h[j] = fmaf(a, h[j], dx * Bv[j]);                             \
            yp = fmaf(h[j], Cv[j], yp);                                   \
        }                                                                 \
        yp = quad_add(yp);                                                \
        if (nq == 0) {                                                    \
            float y = fmaf(Dd, xv, yp);                                   \
            py[dd] = (bf16_t)(y * sz);                                    \
        }                                                                 \
        py += D_MODEL;                                                    \
    }

    for (int g = 0; g < L_CHUNK / PF - 1; ++g) {
        #pragma unroll
        for (int u = 0; u < PF; ++u) {
            float da = p_da[u], xv = p_xv[u], sz = p_sz[u];
            f32x4 Bv = p_B[u], Cv = p_C[u];
            p_da[u] = pr[dd];
            p_B[u]  = *(const f32x4*)(pr + offB);
            p_C[u]  = *(const f32x4*)(pr + offC);
            p_xv[u] = (float)px[dd];
            p_sz[u] = (float)pz[dd];
            pr += N_PAD; px += D_MODEL; pz += 2048;
            P3_STEP(da, xv, sz, Bv, Cv)
        }
    }
    #pragma unroll
    for (int u = 0; u < PF; ++u) {   // final group, no prefetch
        float da = p_da[u], xv = p_xv[u], sz = p_sz[u];
        f32x4 Bv = p_B[u], Cv = p_C[u];
        P3_STEP(da, xv, sz, Bv, Cv)
    }
#undef P3_STEP
}

// ---------------------------------------------------------------------------
extern "C" void kernel_launch(void* const* d_in, const int* in_sizes, int n_in,
                              void* d_out, int out_size, void* d_ws, size_t ws_size,
                              hipStream_t stream)
{
    const float* x    = (const float*)d_in[0];
    const float* h0   = (const float*)d_in[1];
    const float* nw   = (const float*)d_in[2];
    const float* w_in = (const float*)d_in[3];
    const float* cw   = (const float*)d_in[4];
    const float* cb   = (const float*)d_in[5];
    const float* w_x  = (const float*)d_in[6];
    const float* alog = (const float*)d_in[7];
    const float* dv   = (const float*)d_in[8];
    const float* w_out= (const float*)d_in[9];
    float* out  = (float*)d_out;
    float* hout = out + (size_t)N_ROWS * D_MODEL;

    char* ws = (char*)d_ws;
    size_t off = 0;
    auto alloc = [&](size_t bytes) -> void* {
        void* p = ws + off;
        off += (bytes + 255) & ~(size_t)255;
        return p;
    };
    bf16_t* W1  = (bf16_t*)alloc((size_t)4096 * 2048 * 2);   // in_proj bf16
    bf16_t* W2  = (bf16_t*)alloc((size_t)N_PAD * 2048 * 2);  // x_proj bf16 padded
    bf16_t* W3  = (bf16_t*)alloc((size_t)2048 * 2048 * 2);   // out_proj bf16
    bf16_t* XN  = (bf16_t*)alloc((size_t)N_ROWS * 2048 * 2); // normed x bf16
    float*  XB  = (float*) alloc((size_t)N_ROWS * 2048 * 4); // x-branch fp32
    bf16_t* ZG  = (bf16_t*)alloc((size_t)N_ROWS * 2048 * 2); // silu(z) bf16
    float*  PROJ= (float*) alloc((size_t)N_ROWS * N_PAD * 4);// x_proj out (da|B|C)
    float* APROD= (float*) alloc((size_t)N_CHUNK * 4096 * D_STATE * 4);
    float* HFIN = (float*) alloc((size_t)N_CHUNK * 4096 * D_STATE * 4);
    // aliases (lifetimes disjoint in stream order):
    bf16_t* XSb = W1;   // conv bf16 out (W1 dead after GEMM1; lives thru scan)
    bf16_t* YG  = XN;   // gated y bf16  (XN dead after GEMM1)

    // weight casts
    cast_w13<<<(4096 * 2048 / 4 + 2048 * 2048 / 4) / 256, 256, 0, stream>>>(w_in, w_out, W1, W3);
    cast_pad_w2<<<(N_PAD * 2048) / 256, 256, 0, stream>>>(w_x, W2);

    // 1) rmsnorm
    rmsnorm_kernel<<<N_ROWS, 256, 0, stream>>>(x, nw, XN);
    // 2) xz = xn @ W_in^T; epilogue splits x fp32 / silu(z) bf16
    gemm_bt<<<dim3(16, 16), 512, 0, stream>>>(XN, W1, 2048, XB, ZG);
    // 3) conv + silu (bf16 out)
    conv_silu_kernel<<<(B_SZ * (T_LEN / 8) * D_MODEL) / 256, 256, 0, stream>>>(XB, cw, cb, XSb);
    // 4) proj = xssm @ W_x^T; 128^2 grid-filling kernel; softplus epilogue
    gemm128<1><<<dim3(32, N_PAD / 128), 256, 0, stream>>>(XSb, W2, 2048, PROJ, nullptr);
    // 5) chunked scan: 8192 waves, scalar-base addressing, depth-8 prefetch
    scan_phase1<<<2048, 256, 0, stream>>>(PROJ, XSb, alog, APROD, HFIN);
    scan_phase2<<<256, 256, 0, stream>>>(h0, APROD, HFIN, hout);
    scan_phase3<<<2048, 256, 0, stream>>>(PROJ, XSb, ZG, alog, dv, HFIN, YG);
    // 6) out = x + yg @ W_out^T; 128^2 grid-filling kernel
    gemm128<2><<<dim3(32, 16), 256, 0, stream>>>(YG, W3, 2048, out, x);

    (void)in_sizes; (void)n_in; (void)out_size; (void)ws_size;
}